// Round 5
// baseline (223.882 us; speedup 1.0000x reference)
//
#include <hip/hip_runtime.h>
#include <hip/hip_cooperative_groups.h>
#include <math.h>

namespace cg = cooperative_groups;

#define HH 1024
#define WW 1024
#define CD 900
#define MS 10
#define CS 62            // (H-CD)/2
#define OFFT 72          // MS+CS
#define TW 880           // H-2*OFF
#define SS 21            // 2*MS+1
#define EPSV 1e-8
#define NBAND 55         // 880/16 bands of template rows
#define RPB 16           // template rows per corr unit
#define NCH 55           // 880/16 column chunks of 16
#define NCORR (SS * NBAND)       // 1155 corr units
#define NSTAT (CD + TW)          // 1780 stat units
#define TOTAL_A (NCORR + NSTAT)  // 2935

// ws float offsets
#define O_RS1T 0
#define O_RS2T 18900
#define O_TROW1 37800
#define O_TROW2 38680
#define O_SFULL 39560
#define O_PART 40460             // 21*55*21 = 24255
#define O_NCC 64715              // 441

union SharedU {
    float redf[4][SS];
    double redd[4][6];
    struct {
        float sv[256];
        int si[256];
        float sxy[2];
        float tile[32][33];
    } c;
};

__global__ __launch_bounds__(256, 4) void fused_kernel(const float* __restrict__ X,
                                                       const float* __restrict__ T,
                                                       float* __restrict__ ws,
                                                       float* __restrict__ out) {
    float* RS1T = ws + O_RS1T;
    float* RS2T = ws + O_RS2T;
    float* Trow1 = ws + O_TROW1;
    float* Trow2 = ws + O_TROW2;
    float* Sfull = ws + O_SFULL;
    float* part = ws + O_PART;
    float* ncc = ws + O_NCC;

    __shared__ SharedU su;
    const int tid = threadIdx.x;
    const int lane = tid & 63, wid = tid >> 6;
    cg::grid_group grid = cg::this_grid();

    // ================= Phase A: corr units + row stats =================
    for (int vb = blockIdx.x; vb < TOTAL_A; vb += gridDim.x) {
        if (vb < NCORR) {
            // ---- raw cross-correlation unit: (i, band) ----
            const int i = vb / NBAND;
            const int band = vb - i * NBAND;
            const int u0 = band * RPB;
            float acc[SS];
#pragma unroll
            for (int j = 0; j < SS; ++j) acc[j] = 0.f;
#pragma unroll 1
            for (int item = tid; item < RPB * NCH; item += 256) {
                const int ul = item / NCH;
                const int c = item - ul * NCH;
                const int u = u0 + ul;
                // x cols [60+16c, 100+16c): 16B-aligned; needed cols 62+16c+j+k
                const float4* xp = (const float4*)(X + (size_t)(CS + i + u) * WW + 60 + c * 16);
                const float4* tp = (const float4*)(T + (size_t)(OFFT + u) * WW + OFFT + c * 16);
                float xr[40], t[16];
#pragma unroll
                for (int k = 0; k < 10; ++k) {
                    float4 q = xp[k];
                    xr[4 * k] = q.x; xr[4 * k + 1] = q.y; xr[4 * k + 2] = q.z; xr[4 * k + 3] = q.w;
                }
#pragma unroll
                for (int k = 0; k < 4; ++k) {
                    float4 q = tp[k];
                    t[4 * k] = q.x; t[4 * k + 1] = q.y; t[4 * k + 2] = q.z; t[4 * k + 3] = q.w;
                }
#pragma unroll
                for (int j = 0; j < SS; ++j) {
                    float a = acc[j];
#pragma unroll
                    for (int k = 0; k < 16; ++k) a = fmaf(xr[2 + j + k], t[k], a);
                    acc[j] = a;
                }
            }
#pragma unroll
            for (int j = 0; j < SS; ++j)
#pragma unroll
                for (int m = 1; m < 64; m <<= 1) acc[j] += __shfl_xor(acc[j], m);
            if (lane == 0) {
#pragma unroll
                for (int j = 0; j < SS; ++j) su.redf[wid][j] = acc[j];
            }
            __syncthreads();
            if (tid < SS) {
                float s = su.redf[0][tid] + su.redf[1][tid] + su.redf[2][tid] + su.redf[3][tid];
                part[(i * NBAND + band) * SS + tid] = s;
            }
        } else {
            const int b = vb - NCORR;
            if (b < CD) {
                // ---- X crop row: full sum + 21 sliding-window sums ----
                const float* row = X + (size_t)(CS + b) * WW + CS;
                float sf = 0.f, sw = 0.f, qw = 0.f;
                for (int v = tid; v < CD; v += 256) {
                    float x = row[v];
                    sf += x;
                    if (v < TW) { sw += x; qw += x * x; }
                }
                for (int m = 1; m < 64; m <<= 1) {
                    sf += __shfl_xor(sf, m); sw += __shfl_xor(sw, m); qw += __shfl_xor(qw, m);
                }
                if (lane == 0) { su.redf[wid][0] = sf; su.redf[wid][1] = sw; su.redf[wid][2] = qw; }
                __syncthreads();
                if (tid < 32) {
                    const float swb = su.redf[0][1] + su.redf[1][1] + su.redf[2][1] + su.redf[3][1];
                    const float qwb = su.redf[0][2] + su.redf[1][2] + su.redf[2][2] + su.redf[3][2];
                    float d1 = 0.f, d2 = 0.f;
                    if (tid >= 1 && tid < SS) {
                        float a = row[tid - 1], c2 = row[TW + tid - 1];
                        d1 = c2 - a;
                        d2 = c2 * c2 - a * a;
                    }
                    for (int off = 1; off < 32; off <<= 1) {
                        float u1 = __shfl_up(d1, off), u2 = __shfl_up(d2, off);
                        if (tid >= off) { d1 += u1; d2 += u2; }
                    }
                    if (tid < SS) {
                        RS1T[tid * CD + b] = swb + d1;
                        RS2T[tid * CD + b] = qwb + d2;
                    }
                    if (tid == 0)
                        Sfull[b] = su.redf[0][0] + su.redf[1][0] + su.redf[2][0] + su.redf[3][0];
                }
            } else {
                // ---- template row sums ----
                const int u = b - CD;
                const float* row = T + (size_t)(OFFT + u) * WW + OFFT;
                float s = 0.f, q = 0.f;
                for (int v = tid; v < TW; v += 256) { float t = row[v]; s += t; q += t * t; }
                for (int m = 1; m < 64; m <<= 1) { s += __shfl_xor(s, m); q += __shfl_xor(q, m); }
                if (lane == 0) { su.redf[wid][0] = s; su.redf[wid][1] = q; }
                __syncthreads();
                if (tid == 0) {
                    Trow1[u] = su.redf[0][0] + su.redf[1][0] + su.redf[2][0] + su.redf[3][0];
                    Trow2[u] = su.redf[0][1] + su.redf[1][1] + su.redf[2][1] + su.redf[3][1];
                }
            }
        }
        __syncthreads();
    }

    grid.sync();

    // ================= Phase B: combine -> ncc =================
    for (int vb = blockIdx.x; vb < SS * SS; vb += gridDim.x) {
        const int i = vb / SS, j = vb - i * SS;
        double dd = 0, d1 = 0, d2 = 0, ta = 0, tb = 0, xs = 0;
        for (int b = tid; b < NBAND; b += 256) dd += (double)part[(i * NBAND + b) * SS + j];
        const float* r1 = RS1T + j * CD + i;
        const float* r2 = RS2T + j * CD + i;
        for (int u = tid; u < TW; u += 256) {
            d1 += (double)r1[u]; d2 += (double)r2[u];
            ta += (double)Trow1[u]; tb += (double)Trow2[u];
        }
        for (int k = tid; k < CD; k += 256) xs += (double)Sfull[k];
        for (int m = 1; m < 64; m <<= 1) {
            dd += __shfl_xor(dd, m); d1 += __shfl_xor(d1, m); d2 += __shfl_xor(d2, m);
            ta += __shfl_xor(ta, m); tb += __shfl_xor(tb, m); xs += __shfl_xor(xs, m);
        }
        if (lane == 0) {
            su.redd[wid][0] = dd; su.redd[wid][1] = d1; su.redd[wid][2] = d2;
            su.redd[wid][3] = ta; su.redd[wid][4] = tb; su.redd[wid][5] = xs;
        }
        __syncthreads();
        if (tid == 0) {
            double dot = su.redd[0][0] + su.redd[1][0] + su.redd[2][0] + su.redd[3][0];
            double S1 = su.redd[0][1] + su.redd[1][1] + su.redd[2][1] + su.redd[3][1];
            double S2 = su.redd[0][2] + su.redd[1][2] + su.redd[2][2] + su.redd[3][2];
            double sum_t = su.redd[0][3] + su.redd[1][3] + su.redd[2][3] + su.redd[3][3];
            double sum_t2 = su.redd[0][4] + su.redd[1][4] + su.redd[2][4] + su.redd[3][4];
            double sumX = su.redd[0][5] + su.redd[1][5] + su.redd[2][5] + su.redd[3][5];
            const double NT = 774400.0;
            double mt = sum_t / NT, mx = sumX / 810000.0;
            double tvar = sum_t2 - sum_t * sum_t / NT + EPSV;
            double var = S2 - S1 * S1 / NT + EPSV;
            if (var < 0.0) var = 0.0;
            double cross = dot - mt * S1 - mx * sum_t + NT * mx * mt;
            float val = (float)(cross / sqrt(tvar * var));
            if (isnan(val)) val = 0.f;
            ncc[i * SS + j] = val;
        }
        __syncthreads();
    }

    grid.sync();

    // ================= Phase C: argmax/subpixel + bilinear shift =================
    {
        float v = -1e30f; int vi = 0;
        for (int k = tid; k < SS * SS; k += 256) {
            float q = ncc[k];
            if (q > v) { v = q; vi = k; }
        }
        su.c.sv[tid] = v; su.c.si[tid] = vi;
        __syncthreads();
        for (int off = 128; off > 0; off >>= 1) {
            if (tid < off) {
                float v2 = su.c.sv[tid + off]; int i2 = su.c.si[tid + off];
                if (v2 > su.c.sv[tid] || (v2 == su.c.sv[tid] && i2 < su.c.si[tid])) {
                    su.c.sv[tid] = v2; su.c.si[tid] = i2;
                }
            }
            __syncthreads();
        }
        if (tid == 0) {
            int idx = su.c.si[0];
            int sx = idx / SS;
            int sy = idx - sx * SS;
            auto at = [&](int r, int c) -> float {
                r = r < 0 ? 0 : (r > SS - 1 ? SS - 1 : r);
                c = c < 0 ? 0 : (c > SS - 1 ? SS - 1 : c);
                return logf(ncc[r * SS + c]);
            };
            float l4 = 4.0f * at(sx, sy);
            float lxm = at(sx - 1, sy), lxp = at(sx + 1, sy);
            float lym = at(sx, sy - 1), lyp = at(sx, sy + 1);
            float xsv = -((float)sx - (float)MS) - (lxm - lxp) / (2.0f * lxm - l4 + 2.0f * lxp);
            float ysv = -((float)sy - (float)MS) - (lym - lyp) / (2.0f * lym - l4 + 2.0f * lyp);
            su.c.sxy[0] = xsv; su.c.sxy[1] = ysv;
            if (blockIdx.x == 0) {
                out[(size_t)HH * WW] = xsv;
                out[(size_t)HH * WW + 1] = ysv;
            }
        }
        __syncthreads();
    }
    const float xs = su.c.sxy[0], ys = su.c.sxy[1];

    for (int vt = blockIdx.x; vt < 1024; vt += gridDim.x) {
        const int bx = vt & 31, by = vt >> 5;
        const int R0 = by * 32, C0 = bx * 32;
        {
            const int cl = tid & 31, rg = tid >> 5;
            const int c = C0 + cl;
            const float cc = (float)c - ys;
            const float c0f = floorf(cc);
            const float wc = cc - c0f;
            const int c0 = (int)c0f;
            const bool vc0 = (c0 >= 0) & (c0 < WW);
            const bool vc1 = (c0 + 1 >= 0) & (c0 + 1 < WW);
            const int c0c = c0 < 0 ? 0 : (c0 > WW - 1 ? WW - 1 : c0);
            const int c1c = (c0 + 1) < 0 ? 0 : ((c0 + 1) > WW - 1 ? WW - 1 : c0 + 1);
#pragma unroll
            for (int k = 0; k < 4; ++k) {
                const int rl = rg * 4 + k;
                const int r = R0 + rl;
                const float rr = (float)r - xs;
                const float r0f = floorf(rr);
                const float wr = rr - r0f;
                const int r0 = (int)r0f;
                const bool vr0 = (r0 >= 0) & (r0 < HH);
                const bool vr1 = (r0 + 1 >= 0) & (r0 + 1 < HH);
                const int r0c = r0 < 0 ? 0 : (r0 > HH - 1 ? HH - 1 : r0);
                const int r1c = (r0 + 1) < 0 ? 0 : ((r0 + 1) > HH - 1 ? HH - 1 : r0 + 1);
                float s00 = X[(size_t)r0c * WW + c0c]; if (!(vr0 & vc0)) s00 = 0.f;
                float s01 = X[(size_t)r0c * WW + c1c]; if (!(vr0 & vc1)) s01 = 0.f;
                float s10 = X[(size_t)r1c * WW + c0c]; if (!(vr1 & vc0)) s10 = 0.f;
                float s11 = X[(size_t)r1c * WW + c1c]; if (!(vr1 & vc1)) s11 = 0.f;
                su.c.tile[rl][cl] = (1.f - wr) * (1.f - wc) * s00 + (1.f - wr) * wc * s01 +
                                    wr * (1.f - wc) * s10 + wr * wc * s11;
            }
        }
        __syncthreads();
        {
            const int rl = tid & 31, cg2 = tid >> 5;
#pragma unroll
            for (int k = 0; k < 4; ++k) {
                const int cl = cg2 * 4 + k;
                out[(size_t)(C0 + cl) * HH + R0 + rl] = su.c.tile[rl][cl];
            }
        }
        __syncthreads();
    }
}

extern "C" void kernel_launch(void* const* d_in, const int* in_sizes, int n_in,
                              void* d_out, int out_size, void* d_ws, size_t ws_size,
                              hipStream_t stream) {
    const float* X = (const float*)d_in[0];
    const float* T = (const float*)d_in[1];
    float* out = (float*)d_out;
    float* ws = (float*)d_ws;

    int nb = 0;
    hipError_t e = hipOccupancyMaxActiveBlocksPerMultiprocessor(&nb, fused_kernel, 256, 0);
    if (e != hipSuccess || nb < 1) nb = 2;
    int grid = nb * 256;              // 256 CUs
    if (grid > 1024) grid = 1024;

    void* args[] = {(void*)&X, (void*)&T, (void*)&ws, (void*)&out};
    hipLaunchCooperativeKernel(fused_kernel, dim3(grid), dim3(256), args, 0, stream);
}

// Round 6
// 146.694 us; speedup vs baseline: 1.5262x; 1.5262x over previous
//
#include <hip/hip_runtime.h>
#include <math.h>

#define HH 1024
#define WW 1024
#define CD 900
#define MS 10
#define CS 62            // (H-CD)/2
#define OFFT 72          // MS+CS
#define TW 880           // H-2*OFF
#define SS 21            // 2*MS+1
#define EPSV 1e-8
#define NBAND 55         // 880/16 bands of template rows
#define RPB 16           // template rows per corr block
#define NCH 55           // 880/16 column chunks of 16
#define NITEMS (RPB * NCH)       // 880 items per corr block
#define NCORR (SS * NBAND)       // 1155 corr blocks
#define NSTAT (CD + TW)          // 1780 stat blocks

// ws float offsets
#define O_RS1T 0
#define O_RS2T 18900
#define O_TROW1 37800
#define O_TROW2 38680
#define O_SFULL 39560
#define O_PART 40460             // 21*55*21 = 24255
#define O_NCC 64715              // 441

// Load one item's x-window (40 floats) and t-chunk (16 floats) into register arrays.
// Macro (not lambda) so SROA keeps the arrays in VGPRs.
#define LOAD_ITEM(XR, TT, ITEM)                                                      \
    {                                                                                \
        const int ul_ = (ITEM) / NCH;                                                \
        const int c_ = (ITEM) - ul_ * NCH;                                           \
        const int u_ = u0 + ul_;                                                     \
        const float4* xp_ = (const float4*)(X + (size_t)(CS + i + u_) * WW + 60 + c_ * 16); \
        const float4* tp_ = (const float4*)(T + (size_t)(OFFT + u_) * WW + OFFT + c_ * 16); \
        _Pragma("unroll") for (int k_ = 0; k_ < 10; ++k_) {                          \
            float4 q_ = xp_[k_];                                                     \
            XR[4 * k_] = q_.x; XR[4 * k_ + 1] = q_.y;                                \
            XR[4 * k_ + 2] = q_.z; XR[4 * k_ + 3] = q_.w;                            \
        }                                                                            \
        _Pragma("unroll") for (int k_ = 0; k_ < 4; ++k_) {                           \
            float4 q_ = tp_[k_];                                                     \
            TT[4 * k_] = q_.x; TT[4 * k_ + 1] = q_.y;                                \
            TT[4 * k_ + 2] = q_.z; TT[4 * k_ + 3] = q_.w;                            \
        }                                                                            \
    }

#define FMA_ITEM(XR, TT)                                                             \
    {                                                                                \
        _Pragma("unroll") for (int j_ = 0; j_ < SS; ++j_) {                          \
            float a_ = acc[j_];                                                      \
            _Pragma("unroll") for (int k_ = 0; k_ < 16; ++k_)                        \
                a_ = fmaf(XR[2 + j_ + k_], TT[k_], a_);                              \
            acc[j_] = a_;                                                            \
        }                                                                            \
    }

// ---------------- corr + row stats in one dispatch ----------------
__global__ __launch_bounds__(256, 3) void corr_stats_kernel(const float* __restrict__ X,
                                                            const float* __restrict__ T,
                                                            float* __restrict__ ws) {
    float* RS1T = ws + O_RS1T;
    float* RS2T = ws + O_RS2T;
    float* Trow1 = ws + O_TROW1;
    float* Trow2 = ws + O_TROW2;
    float* Sfull = ws + O_SFULL;
    float* part = ws + O_PART;

    const int tid = threadIdx.x;
    const int lane = tid & 63, wid = tid >> 6;
    __shared__ float red[4][SS];

    if (blockIdx.x < NCORR) {
        // ---- raw cross-correlation block (i, band), software-pipelined ----
        const int vb = blockIdx.x;
        const int i = vb / NBAND;
        const int band = vb - i * NBAND;
        const int u0 = band * RPB;

        float acc[SS];
#pragma unroll
        for (int j = 0; j < SS; ++j) acc[j] = 0.f;

        // items/thread: tid, tid+256, tid+512 always valid (<=767<880);
        // tid+768 valid iff tid<112.  2-deep ping-pong: loads of item n+1
        // are in flight during FMA of item n.
        float xrA[40], ttA[16], xrB[40], ttB[16];
        LOAD_ITEM(xrA, ttA, tid)
        LOAD_ITEM(xrB, ttB, tid + 256)
        FMA_ITEM(xrA, ttA)
        LOAD_ITEM(xrA, ttA, tid + 512)
        FMA_ITEM(xrB, ttB)
        if (tid < NITEMS - 768) {
            LOAD_ITEM(xrB, ttB, tid + 768)
        }
        FMA_ITEM(xrA, ttA)
        if (tid < NITEMS - 768) {
            FMA_ITEM(xrB, ttB)
        }

#pragma unroll
        for (int j = 0; j < SS; ++j)
#pragma unroll
            for (int m = 1; m < 64; m <<= 1) acc[j] += __shfl_xor(acc[j], m);
        if (lane == 0) {
#pragma unroll
            for (int j = 0; j < SS; ++j) red[wid][j] = acc[j];
        }
        __syncthreads();
        if (tid < SS) {
            float s = red[0][tid] + red[1][tid] + red[2][tid] + red[3][tid];
            part[(i * NBAND + band) * SS + tid] = s;
        }
    } else {
        const int b = blockIdx.x - NCORR;
        if (b < CD) {
            // ---- X crop row: full sum + 21 sliding-window sums ----
            const float* row = X + (size_t)(CS + b) * WW + CS;
            float sf = 0.f, sw = 0.f, qw = 0.f;
            for (int v = tid; v < CD; v += 256) {
                float x = row[v];
                sf += x;
                if (v < TW) { sw += x; qw += x * x; }
            }
            for (int m = 1; m < 64; m <<= 1) {
                sf += __shfl_xor(sf, m); sw += __shfl_xor(sw, m); qw += __shfl_xor(qw, m);
            }
            if (lane == 0) { red[wid][0] = sf; red[wid][1] = sw; red[wid][2] = qw; }
            __syncthreads();
            if (tid < 32) {
                const float swb = red[0][1] + red[1][1] + red[2][1] + red[3][1];
                const float qwb = red[0][2] + red[1][2] + red[2][2] + red[3][2];
                float d1 = 0.f, d2 = 0.f;
                if (tid >= 1 && tid < SS) {
                    float a = row[tid - 1], c2 = row[TW + tid - 1];
                    d1 = c2 - a;
                    d2 = c2 * c2 - a * a;
                }
                for (int off = 1; off < 32; off <<= 1) {
                    float u1 = __shfl_up(d1, off), u2 = __shfl_up(d2, off);
                    if (tid >= off) { d1 += u1; d2 += u2; }
                }
                if (tid < SS) {
                    RS1T[tid * CD + b] = swb + d1;
                    RS2T[tid * CD + b] = qwb + d2;
                }
                if (tid == 0) Sfull[b] = red[0][0] + red[1][0] + red[2][0] + red[3][0];
            }
        } else {
            // ---- template row sums ----
            const int u = b - CD;
            const float* row = T + (size_t)(OFFT + u) * WW + OFFT;
            float s = 0.f, q = 0.f;
            for (int v = tid; v < TW; v += 256) { float t = row[v]; s += t; q += t * t; }
            for (int m = 1; m < 64; m <<= 1) { s += __shfl_xor(s, m); q += __shfl_xor(q, m); }
            if (lane == 0) { red[wid][0] = s; red[wid][1] = q; }
            __syncthreads();
            if (tid == 0) {
                Trow1[u] = red[0][0] + red[1][0] + red[2][0] + red[3][0];
                Trow2[u] = red[0][1] + red[1][1] + red[2][1] + red[3][1];
            }
        }
    }
}

// ---------------- combine -> ncc ----------------
__global__ __launch_bounds__(256) void ncc_final_kernel(const float* __restrict__ ws,
                                                        float* __restrict__ ncc) {
    const float* RS1T = ws + O_RS1T;
    const float* RS2T = ws + O_RS2T;
    const float* Trow1 = ws + O_TROW1;
    const float* Trow2 = ws + O_TROW2;
    const float* Sfull = ws + O_SFULL;
    const float* part = ws + O_PART;

    const int bid = blockIdx.x;
    const int i = bid / SS, j = bid - i * SS;
    const int tid = threadIdx.x;
    double dd = 0, d1 = 0, d2 = 0, ta = 0, tb = 0, xs = 0;
    for (int b = tid; b < NBAND; b += 256) dd += (double)part[(i * NBAND + b) * SS + j];
    const float* r1 = RS1T + j * CD + i;
    const float* r2 = RS2T + j * CD + i;
    for (int u = tid; u < TW; u += 256) {
        d1 += (double)r1[u]; d2 += (double)r2[u];
        ta += (double)Trow1[u]; tb += (double)Trow2[u];
    }
    for (int k = tid; k < CD; k += 256) xs += (double)Sfull[k];
    for (int m = 1; m < 64; m <<= 1) {
        dd += __shfl_xor(dd, m); d1 += __shfl_xor(d1, m); d2 += __shfl_xor(d2, m);
        ta += __shfl_xor(ta, m); tb += __shfl_xor(tb, m); xs += __shfl_xor(xs, m);
    }
    __shared__ double red[4][6];
    const int lane = tid & 63, wid = tid >> 6;
    if (lane == 0) {
        red[wid][0] = dd; red[wid][1] = d1; red[wid][2] = d2;
        red[wid][3] = ta; red[wid][4] = tb; red[wid][5] = xs;
    }
    __syncthreads();
    if (tid == 0) {
        double dot = red[0][0] + red[1][0] + red[2][0] + red[3][0];
        double S1 = red[0][1] + red[1][1] + red[2][1] + red[3][1];
        double S2 = red[0][2] + red[1][2] + red[2][2] + red[3][2];
        double sum_t = red[0][3] + red[1][3] + red[2][3] + red[3][3];
        double sum_t2 = red[0][4] + red[1][4] + red[2][4] + red[3][4];
        double sumX = red[0][5] + red[1][5] + red[2][5] + red[3][5];
        const double NT = 774400.0;
        double mt = sum_t / NT, mx = sumX / 810000.0;
        double tvar = sum_t2 - sum_t * sum_t / NT + EPSV;
        double var = S2 - S1 * S1 / NT + EPSV;
        if (var < 0.0) var = 0.0;
        double cross = dot - mt * S1 - mx * sum_t + NT * mx * mt;
        float val = (float)(cross / sqrt(tvar * var));
        if (isnan(val)) val = 0.f;
        ncc[i * SS + j] = val;
    }
}

// ---------------- shift with fused argmax+subpixel (redundant per block) ----------
__global__ __launch_bounds__(256) void shift_kernel(const float* __restrict__ img,
                                                    const float* __restrict__ ncc,
                                                    float* __restrict__ out) {
    __shared__ float sv[256];
    __shared__ int si[256];
    __shared__ float sxy[2];
    __shared__ float tile[64][65];
    const int tid = threadIdx.x;

    {
        float v = -1e30f; int vi = 0;
        for (int k = tid; k < SS * SS; k += 256) {
            float q = ncc[k];
            if (q > v) { v = q; vi = k; }
        }
        sv[tid] = v; si[tid] = vi;
        __syncthreads();
        for (int off = 128; off > 0; off >>= 1) {
            if (tid < off) {
                float v2 = sv[tid + off]; int i2 = si[tid + off];
                if (v2 > sv[tid] || (v2 == sv[tid] && i2 < si[tid])) { sv[tid] = v2; si[tid] = i2; }
            }
            __syncthreads();
        }
        if (tid == 0) {
            int idx = si[0];
            int sx = idx / SS;
            int sy = idx - sx * SS;
            auto at = [&](int r, int c) -> float {
                r = r < 0 ? 0 : (r > SS - 1 ? SS - 1 : r);
                c = c < 0 ? 0 : (c > SS - 1 ? SS - 1 : c);
                return logf(ncc[r * SS + c]);
            };
            float l4 = 4.0f * at(sx, sy);
            float lxm = at(sx - 1, sy), lxp = at(sx + 1, sy);
            float lym = at(sx, sy - 1), lyp = at(sx, sy + 1);
            float xsv = -((float)sx - (float)MS) - (lxm - lxp) / (2.0f * lxm - l4 + 2.0f * lxp);
            float ysv = -((float)sy - (float)MS) - (lym - lyp) / (2.0f * lym - l4 + 2.0f * lyp);
            sxy[0] = xsv; sxy[1] = ysv;
            if (blockIdx.x == 0 && blockIdx.y == 0) {
                out[(size_t)HH * WW] = xsv;
                out[(size_t)HH * WW + 1] = ysv;
            }
        }
        __syncthreads();
    }

    const float xs = sxy[0], ys = sxy[1];
    const int R0 = blockIdx.y * 64, C0 = blockIdx.x * 64;
    {
        const int cl = tid & 63, rg = tid >> 6;
        const int c = C0 + cl;
        const float cc = (float)c - ys;
        const float c0f = floorf(cc);
        const float wc = cc - c0f;
        const int c0 = (int)c0f;
        const bool vc0 = (c0 >= 0) & (c0 < WW);
        const bool vc1 = (c0 + 1 >= 0) & (c0 + 1 < WW);
        const int c0c = c0 < 0 ? 0 : (c0 > WW - 1 ? WW - 1 : c0);
        const int c1c = (c0 + 1) < 0 ? 0 : ((c0 + 1) > WW - 1 ? WW - 1 : c0 + 1);
        for (int k = 0; k < 16; ++k) {
            const int rl = rg * 16 + k;
            const int r = R0 + rl;
            const float rr = (float)r - xs;
            const float r0f = floorf(rr);
            const float wr = rr - r0f;
            const int r0 = (int)r0f;
            const bool vr0 = (r0 >= 0) & (r0 < HH);
            const bool vr1 = (r0 + 1 >= 0) & (r0 + 1 < HH);
            const int r0c = r0 < 0 ? 0 : (r0 > HH - 1 ? HH - 1 : r0);
            const int r1c = (r0 + 1) < 0 ? 0 : ((r0 + 1) > HH - 1 ? HH - 1 : r0 + 1);
            float s00 = img[(size_t)r0c * WW + c0c]; if (!(vr0 & vc0)) s00 = 0.f;
            float s01 = img[(size_t)r0c * WW + c1c]; if (!(vr0 & vc1)) s01 = 0.f;
            float s10 = img[(size_t)r1c * WW + c0c]; if (!(vr1 & vc0)) s10 = 0.f;
            float s11 = img[(size_t)r1c * WW + c1c]; if (!(vr1 & vc1)) s11 = 0.f;
            tile[rl][cl] = (1.f - wr) * (1.f - wc) * s00 + (1.f - wr) * wc * s01 +
                           wr * (1.f - wc) * s10 + wr * wc * s11;
        }
    }
    __syncthreads();
    {
        const int rl = tid & 63, cg = tid >> 6;
        for (int k = 0; k < 16; ++k) {
            const int cl = cg * 16 + k;
            out[(size_t)(C0 + cl) * HH + R0 + rl] = tile[rl][cl];
        }
    }
}

extern "C" void kernel_launch(void* const* d_in, const int* in_sizes, int n_in,
                              void* d_out, int out_size, void* d_ws, size_t ws_size,
                              hipStream_t stream) {
    const float* X = (const float*)d_in[0];
    const float* T = (const float*)d_in[1];
    float* out = (float*)d_out;
    float* ws = (float*)d_ws;
    float* ncc = ws + O_NCC;

    corr_stats_kernel<<<NCORR + NSTAT, 256, 0, stream>>>(X, T, ws);
    ncc_final_kernel<<<SS * SS, 256, 0, stream>>>(ws, ncc);
    shift_kernel<<<dim3(16, 16), 256, 0, stream>>>(X, ncc, out);
}

// Round 7
// 101.151 us; speedup vs baseline: 2.2133x; 1.4502x over previous
//
#include <hip/hip_runtime.h>
#include <math.h>

#define HH 1024
#define WW 1024
#define CD 900
#define MS 10
#define CS 62            // (H-CD)/2
#define OFFT 72          // MS+CS
#define TW 880           // H-2*OFF
#define SS 21            // 2*MS+1
#define EPSV 1e-8
#define NBAND 55         // 880/16 bands of template rows
#define RPB 16           // template rows per corr block
#define NCORR (SS * NBAND)       // 1155 corr blocks
#define NSTAT (CD + TW)          // 1780 stat blocks

// ws float offsets
#define O_RS1T 0
#define O_RS2T 18900
#define O_TROW1 37800
#define O_TROW2 38680
#define O_SFULL 39560
#define O_PART 40460             // 21*55*21 = 24255
#define O_NCC 64715              // 441

// ---------------- corr + row stats in one dispatch ----------------
// corr block b = band*SS + i (band-major: blocks sharing a band reuse the same
// X-rows/T-rows in L2). Wave-item = (row ul, 256-col segment seg); lane l owns
// t-cols seg*256+4l..+3 -> ALL global loads at 16B lane stride (coalesced).
__global__ __launch_bounds__(256, 4) void corr_stats_kernel(const float* __restrict__ X,
                                                            const float* __restrict__ T,
                                                            float* __restrict__ ws) {
    float* RS1T = ws + O_RS1T;
    float* RS2T = ws + O_RS2T;
    float* Trow1 = ws + O_TROW1;
    float* Trow2 = ws + O_TROW2;
    float* Sfull = ws + O_SFULL;
    float* part = ws + O_PART;

    const int tid = threadIdx.x;
    const int lane = tid & 63, wid = tid >> 6;
    __shared__ float red[4][SS];

    if (blockIdx.x < NCORR) {
        const int band = blockIdx.x / SS;
        const int i = blockIdx.x - band * SS;
        const int u0 = band * RPB;

        float acc[SS];
#pragma unroll
        for (int j = 0; j < SS; ++j) acc[j] = 0.f;

        // 64 wave-items = 16 rows x 4 segments; each of the 4 waves does 16.
#pragma unroll 1
        for (int m = wid; m < 64; m += 4) {
            const int ul = m >> 2, seg = m & 3;
            const int u = u0 + ul;
            const int tc = seg * 256 + 4 * lane;          // template col of this lane
            // t: 16B-aligned (72 + tc, tc%4==0), coalesced across lanes
            const float4 t4v = *(const float4*)(T + (size_t)(OFFT + u) * WW + OFFT + tc);
            float tt0 = t4v.x, tt1 = t4v.y, tt2 = t4v.z, tt3 = t4v.w;
            if (tc >= TW) { tt0 = 0.f; tt1 = 0.f; tt2 = 0.f; tt3 = 0.f; }  // seg-3 tail
            // x window: crop cols [tc-2, tc+25]; global dword 60+tc is 16B-aligned
            const float4* xp = (const float4*)(X + (size_t)(CS + i + u) * WW + 60 + tc);
            float xr[28];
#pragma unroll
            for (int k = 0; k < 7; ++k) {
                float4 q = xp[k];
                xr[4 * k] = q.x; xr[4 * k + 1] = q.y; xr[4 * k + 2] = q.z; xr[4 * k + 3] = q.w;
            }
            // acc[j] += sum_k t[tc+k] * x_crop[tc+k+j] ; x_crop[tc-2] == xr[0]
#pragma unroll
            for (int j = 0; j < SS; ++j) {
                float a = acc[j];
                a = fmaf(xr[2 + j], tt0, a);
                a = fmaf(xr[3 + j], tt1, a);
                a = fmaf(xr[4 + j], tt2, a);
                a = fmaf(xr[5 + j], tt3, a);
                acc[j] = a;
            }
        }

#pragma unroll
        for (int j = 0; j < SS; ++j)
#pragma unroll
            for (int m = 1; m < 64; m <<= 1) acc[j] += __shfl_xor(acc[j], m);
        if (lane == 0) {
#pragma unroll
            for (int j = 0; j < SS; ++j) red[wid][j] = acc[j];
        }
        __syncthreads();
        if (tid < SS) {
            float s = red[0][tid] + red[1][tid] + red[2][tid] + red[3][tid];
            part[(i * NBAND + band) * SS + tid] = s;
        }
    } else {
        const int b = blockIdx.x - NCORR;
        if (b < CD) {
            // ---- X crop row: full sum + 21 sliding-window sums ----
            const float* row = X + (size_t)(CS + b) * WW + CS;
            float sf = 0.f, sw = 0.f, qw = 0.f;
            for (int v = tid; v < CD; v += 256) {
                float x = row[v];
                sf += x;
                if (v < TW) { sw += x; qw += x * x; }
            }
            for (int m = 1; m < 64; m <<= 1) {
                sf += __shfl_xor(sf, m); sw += __shfl_xor(sw, m); qw += __shfl_xor(qw, m);
            }
            if (lane == 0) { red[wid][0] = sf; red[wid][1] = sw; red[wid][2] = qw; }
            __syncthreads();
            if (tid < 32) {
                const float swb = red[0][1] + red[1][1] + red[2][1] + red[3][1];
                const float qwb = red[0][2] + red[1][2] + red[2][2] + red[3][2];
                float d1 = 0.f, d2 = 0.f;
                if (tid >= 1 && tid < SS) {
                    float a = row[tid - 1], c2 = row[TW + tid - 1];
                    d1 = c2 - a;
                    d2 = c2 * c2 - a * a;
                }
                for (int off = 1; off < 32; off <<= 1) {
                    float u1 = __shfl_up(d1, off), u2 = __shfl_up(d2, off);
                    if (tid >= off) { d1 += u1; d2 += u2; }
                }
                if (tid < SS) {
                    RS1T[tid * CD + b] = swb + d1;
                    RS2T[tid * CD + b] = qwb + d2;
                }
                if (tid == 0) Sfull[b] = red[0][0] + red[1][0] + red[2][0] + red[3][0];
            }
        } else {
            // ---- template row sums ----
            const int u = b - CD;
            const float* row = T + (size_t)(OFFT + u) * WW + OFFT;
            float s = 0.f, q = 0.f;
            for (int v = tid; v < TW; v += 256) { float t = row[v]; s += t; q += t * t; }
            for (int m = 1; m < 64; m <<= 1) { s += __shfl_xor(s, m); q += __shfl_xor(q, m); }
            if (lane == 0) { red[wid][0] = s; red[wid][1] = q; }
            __syncthreads();
            if (tid == 0) {
                Trow1[u] = red[0][0] + red[1][0] + red[2][0] + red[3][0];
                Trow2[u] = red[0][1] + red[1][1] + red[2][1] + red[3][1];
            }
        }
    }
}

// ---------------- combine -> ncc ----------------
__global__ __launch_bounds__(256) void ncc_final_kernel(const float* __restrict__ ws,
                                                        float* __restrict__ ncc) {
    const float* RS1T = ws + O_RS1T;
    const float* RS2T = ws + O_RS2T;
    const float* Trow1 = ws + O_TROW1;
    const float* Trow2 = ws + O_TROW2;
    const float* Sfull = ws + O_SFULL;
    const float* part = ws + O_PART;

    const int bid = blockIdx.x;
    const int i = bid / SS, j = bid - i * SS;
    const int tid = threadIdx.x;
    double dd = 0, d1 = 0, d2 = 0, ta = 0, tb = 0, xs = 0;
    for (int b = tid; b < NBAND; b += 256) dd += (double)part[(i * NBAND + b) * SS + j];
    const float* r1 = RS1T + j * CD + i;
    const float* r2 = RS2T + j * CD + i;
    for (int u = tid; u < TW; u += 256) {
        d1 += (double)r1[u]; d2 += (double)r2[u];
        ta += (double)Trow1[u]; tb += (double)Trow2[u];
    }
    for (int k = tid; k < CD; k += 256) xs += (double)Sfull[k];
    for (int m = 1; m < 64; m <<= 1) {
        dd += __shfl_xor(dd, m); d1 += __shfl_xor(d1, m); d2 += __shfl_xor(d2, m);
        ta += __shfl_xor(ta, m); tb += __shfl_xor(tb, m); xs += __shfl_xor(xs, m);
    }
    __shared__ double red[4][6];
    const int lane = tid & 63, wid = tid >> 6;
    if (lane == 0) {
        red[wid][0] = dd; red[wid][1] = d1; red[wid][2] = d2;
        red[wid][3] = ta; red[wid][4] = tb; red[wid][5] = xs;
    }
    __syncthreads();
    if (tid == 0) {
        double dot = red[0][0] + red[1][0] + red[2][0] + red[3][0];
        double S1 = red[0][1] + red[1][1] + red[2][1] + red[3][1];
        double S2 = red[0][2] + red[1][2] + red[2][2] + red[3][2];
        double sum_t = red[0][3] + red[1][3] + red[2][3] + red[3][3];
        double sum_t2 = red[0][4] + red[1][4] + red[2][4] + red[3][4];
        double sumX = red[0][5] + red[1][5] + red[2][5] + red[3][5];
        const double NT = 774400.0;
        double mt = sum_t / NT, mx = sumX / 810000.0;
        double tvar = sum_t2 - sum_t * sum_t / NT + EPSV;
        double var = S2 - S1 * S1 / NT + EPSV;
        if (var < 0.0) var = 0.0;
        double cross = dot - mt * S1 - mx * sum_t + NT * mx * mt;
        float val = (float)(cross / sqrt(tvar * var));
        if (isnan(val)) val = 0.f;
        ncc[i * SS + j] = val;
    }
}

// ---------------- shift with fused argmax+subpixel (redundant per block) ----------
__global__ __launch_bounds__(256) void shift_kernel(const float* __restrict__ img,
                                                    const float* __restrict__ ncc,
                                                    float* __restrict__ out) {
    __shared__ float sv[256];
    __shared__ int si[256];
    __shared__ float sxy[2];
    __shared__ float tile[64][65];
    const int tid = threadIdx.x;

    {
        float v = -1e30f; int vi = 0;
        for (int k = tid; k < SS * SS; k += 256) {
            float q = ncc[k];
            if (q > v) { v = q; vi = k; }
        }
        sv[tid] = v; si[tid] = vi;
        __syncthreads();
        for (int off = 128; off > 0; off >>= 1) {
            if (tid < off) {
                float v2 = sv[tid + off]; int i2 = si[tid + off];
                if (v2 > sv[tid] || (v2 == sv[tid] && i2 < si[tid])) { sv[tid] = v2; si[tid] = i2; }
            }
            __syncthreads();
        }
        if (tid == 0) {
            int idx = si[0];
            int sx = idx / SS;
            int sy = idx - sx * SS;
            auto at = [&](int r, int c) -> float {
                r = r < 0 ? 0 : (r > SS - 1 ? SS - 1 : r);
                c = c < 0 ? 0 : (c > SS - 1 ? SS - 1 : c);
                return logf(ncc[r * SS + c]);
            };
            float l4 = 4.0f * at(sx, sy);
            float lxm = at(sx - 1, sy), lxp = at(sx + 1, sy);
            float lym = at(sx, sy - 1), lyp = at(sx, sy + 1);
            float xsv = -((float)sx - (float)MS) - (lxm - lxp) / (2.0f * lxm - l4 + 2.0f * lxp);
            float ysv = -((float)sy - (float)MS) - (lym - lyp) / (2.0f * lym - l4 + 2.0f * lyp);
            sxy[0] = xsv; sxy[1] = ysv;
            if (blockIdx.x == 0 && blockIdx.y == 0) {
                out[(size_t)HH * WW] = xsv;
                out[(size_t)HH * WW + 1] = ysv;
            }
        }
        __syncthreads();
    }

    const float xs = sxy[0], ys = sxy[1];
    const int R0 = blockIdx.y * 64, C0 = blockIdx.x * 64;
    {
        const int cl = tid & 63, rg = tid >> 6;
        const int c = C0 + cl;
        const float cc = (float)c - ys;
        const float c0f = floorf(cc);
        const float wc = cc - c0f;
        const int c0 = (int)c0f;
        const bool vc0 = (c0 >= 0) & (c0 < WW);
        const bool vc1 = (c0 + 1 >= 0) & (c0 + 1 < WW);
        const int c0c = c0 < 0 ? 0 : (c0 > WW - 1 ? WW - 1 : c0);
        const int c1c = (c0 + 1) < 0 ? 0 : ((c0 + 1) > WW - 1 ? WW - 1 : c0 + 1);
        for (int k = 0; k < 16; ++k) {
            const int rl = rg * 16 + k;
            const int r = R0 + rl;
            const float rr = (float)r - xs;
            const float r0f = floorf(rr);
            const float wr = rr - r0f;
            const int r0 = (int)r0f;
            const bool vr0 = (r0 >= 0) & (r0 < HH);
            const bool vr1 = (r0 + 1 >= 0) & (r0 + 1 < HH);
            const int r0c = r0 < 0 ? 0 : (r0 > HH - 1 ? HH - 1 : r0);
            const int r1c = (r0 + 1) < 0 ? 0 : ((r0 + 1) > HH - 1 ? HH - 1 : r0 + 1);
            float s00 = img[(size_t)r0c * WW + c0c]; if (!(vr0 & vc0)) s00 = 0.f;
            float s01 = img[(size_t)r0c * WW + c1c]; if (!(vr0 & vc1)) s01 = 0.f;
            float s10 = img[(size_t)r1c * WW + c0c]; if (!(vr1 & vc0)) s10 = 0.f;
            float s11 = img[(size_t)r1c * WW + c1c]; if (!(vr1 & vc1)) s11 = 0.f;
            tile[rl][cl] = (1.f - wr) * (1.f - wc) * s00 + (1.f - wr) * wc * s01 +
                           wr * (1.f - wc) * s10 + wr * wc * s11;
        }
    }
    __syncthreads();
    {
        const int rl = tid & 63, cg = tid >> 6;
        for (int k = 0; k < 16; ++k) {
            const int cl = cg * 16 + k;
            out[(size_t)(C0 + cl) * HH + R0 + rl] = tile[rl][cl];
        }
    }
}

extern "C" void kernel_launch(void* const* d_in, const int* in_sizes, int n_in,
                              void* d_out, int out_size, void* d_ws, size_t ws_size,
                              hipStream_t stream) {
    const float* X = (const float*)d_in[0];
    const float* T = (const float*)d_in[1];
    float* out = (float*)d_out;
    float* ws = (float*)d_ws;
    float* ncc = ws + O_NCC;

    corr_stats_kernel<<<NCORR + NSTAT, 256, 0, stream>>>(X, T, ws);
    ncc_final_kernel<<<SS * SS, 256, 0, stream>>>(ws, ncc);
    shift_kernel<<<dim3(16, 16), 256, 0, stream>>>(X, ncc, out);
}